// Round 1
// baseline (1939.038 us; speedup 1.0000x reference)
//
#include <hip/hip_runtime.h>

#define NB 8192   // tokens
#define NC 1024   // model dim
#define NE 8      // experts
#define NK 4      // top-k
#define NH 4096   // hidden dim
constexpr int ROWCAP = NB * NK + NE * 128;  // padded routed-row capacity

typedef _Float16 f16;
typedef _Float16 f16x8 __attribute__((ext_vector_type(8)));
typedef _Float16 f16x4 __attribute__((ext_vector_type(4)));
typedef float    f32x4 __attribute__((ext_vector_type(4)));

__device__ __forceinline__ void async_cp16(const f16* g, f16* l) {
    __builtin_amdgcn_global_load_lds((const __attribute__((address_space(1))) void*)g,
                                     (__attribute__((address_space(3))) void*)l, 16, 0, 0);
}

__device__ __forceinline__ float quick_gelu(float v) {
    return v / (1.f + __expf(-1.702f * v));
}

// ------------- transpose + cast: in [E][R][S] fp32 -> out [E][S][R] fp16 -------------
__global__ void transpose_cast_k(const float* __restrict__ in, f16* __restrict__ out,
                                 int R, int S) {
    __shared__ f16 tile[32][33];
    int e = blockIdx.z;
    long base = (long)e * R * S;
    int s0 = blockIdx.x * 32, r0 = blockIdx.y * 32;
    int tx = threadIdx.x & 31, ty = threadIdx.x >> 5;  // 32 x 8
    #pragma unroll
    for (int i = 0; i < 32; i += 8)
        tile[ty + i][tx] = (f16)in[base + (long)(r0 + ty + i) * S + s0 + tx];
    __syncthreads();
    #pragma unroll
    for (int i = 0; i < 32; i += 8)
        out[base + (long)(s0 + ty + i) * R + r0 + tx] = tile[tx][ty + i];
}

// ---- gating: logits -> softmax -> top4 -> slot assignment; also casts x -> fp16 ----
__global__ void gating_k(const float* __restrict__ x, const float* __restrict__ Wg,
                         const float* __restrict__ bg, int* __restrict__ counts,
                         int* __restrict__ tokmap, int* __restrict__ eids,
                         int* __restrict__ slots, float* __restrict__ gatew,
                         f16* __restrict__ x16) {
    int b = blockIdx.x, t = threadIdx.x;
    float acc[NE] = {};
    float4 xv = ((const float4*)(x + (long)b * NC))[t];
    f16x4 hx = { (f16)xv.x, (f16)xv.y, (f16)xv.z, (f16)xv.w };
    ((f16x4*)(x16 + (long)b * NC))[t] = hx;
    const float* wr = Wg + (long)t * 4 * NE;
    #pragma unroll
    for (int j = 0; j < 4; j++) {
        float xj = ((const float*)&xv)[j];
        #pragma unroll
        for (int e2 = 0; e2 < NE; e2++) acc[e2] += xj * wr[j * NE + e2];
    }
    #pragma unroll
    for (int e2 = 0; e2 < NE; e2++)
        #pragma unroll
        for (int off = 32; off; off >>= 1) acc[e2] += __shfl_down(acc[e2], off);
    __shared__ float red[4][NE];
    int lane = t & 63, w = t >> 6;
    if (lane == 0)
        for (int e2 = 0; e2 < NE; e2++) red[w][e2] = acc[e2];
    __syncthreads();
    if (t == 0) {
        float l[NE];
        float m = -1e30f;
        for (int e2 = 0; e2 < NE; e2++) {
            l[e2] = red[0][e2] + red[1][e2] + red[2][e2] + red[3][e2] + bg[e2];
            m = fmaxf(m, l[e2]);
        }
        float p[NE], sum = 0.f;
        for (int e2 = 0; e2 < NE; e2++) { p[e2] = __expf(l[e2] - m); sum += p[e2]; }
        float inv = 1.f / sum;
        for (int e2 = 0; e2 < NE; e2++) p[e2] *= inv;
        bool taken[NE] = {};
        for (int k = 0; k < NK; k++) {
            int be = 0; float bv = -1e30f;
            for (int e2 = 0; e2 < NE; e2++)
                if (!taken[e2] && p[e2] > bv) { bv = p[e2]; be = e2; }
            taken[be] = true;
            int slot = atomicAdd(&counts[be], 1);
            tokmap[be * NB + slot] = b;
            eids[b * NK + k] = be;
            slots[b * NK + k] = slot;
            gatew[b * NK + k] = bv;
        }
    }
}

// ---------------- padded prefix offsets ----------------
__global__ void offsets_k(const int* __restrict__ counts, int* __restrict__ offp) {
    if (threadIdx.x == 0 && blockIdx.x == 0) {
        int o = 0;
        for (int e = 0; e < NE; e++) { offp[e] = o; o += ((counts[e] + 127) >> 7) << 7; }
    }
}

// ---------------- 256x256 deep-pipelined GEMM ----------------
// Out[row,n] = quick_gelu(sum_k A[row,k]*Bt[e,n,k] + bias[e,n]), fp16 in/out, fp32 acc.
// Schedule (T3+T4+T5 port of the 8-phase template):
//   - K consumed in 32-wide slabs; 4-deep LDS ring per operand (4 x 16KB A + 4 x 16KB B
//     = 128KB).  Slab layout [256 rows][32 k] f16: row stride 64B -> ds_read_b128
//     fragments are bank-conflict-free with a LINEAR layout (no swizzle; keeps
//     global_load_lds dest legal: base + lane*16, t*8 f16 == linear row-major).
//   - Stage 3 slabs ahead (A in phase A, B in phase B of slab s -> slab s+3 writes the
//     ring slot whose readers finished behind the previous phase barrier: race-free).
//   - Counted vmcnt gate once per slab: steady vmcnt(8) (= 2 ops x 4 newest slab-halves
//     allowed in flight); drain tail vmcnt(4)/vmcnt(0).  Never drains the pipe mid-loop.
//   - 2 raw s_barriers per phase, s_setprio(1) around each 16-MFMA cluster.
// 8 waves (2M x 4N), per-wave 128x64 output, acc[8][4] f32x4.
__global__ __launch_bounds__(512, 2) void gemm256(
    const f16* __restrict__ A, const f16* __restrict__ Bt,
    const float* __restrict__ bias, f16* __restrict__ Out,
    const int* __restrict__ counts, const int* __restrict__ offp,
    const int* __restrict__ tokmap, int Kd, int N, int gather) {
    int e = blockIdx.z;
    int cnt = counts[e];
    int m0 = blockIdx.x << 8;
    if (m0 >= cnt) return;
    int n0 = blockIdx.y << 8;
    int base = offp[e];

    __shared__ __align__(16) f16 smem[65536];   // 128 KB
    f16* As = smem;            // 4 slabs x 8192 f16  (256 rows x 32 k)
    f16* Bs = smem + 32768;    // 4 slabs x 8192 f16  (256 cols x 32 k)

    int t = threadIdx.x;
    int lane = t & 63;
    int w = t >> 6;
    int wr = w >> 2, wc = w & 3;          // wave tile: rows wr*128.., cols wc*64..
    int ml = lane & 15, kq = lane >> 4;   // MFMA fragment lane decomposition

    // ---- staging addresses: thread t covers (row = t>>2 [+128], k-chunk = (t&3)*8) ----
    int sr = t >> 2;
    int sc = (t & 3) << 3;
    int ra = m0 + sr;        if (ra > cnt - 1) ra = cnt - 1;
    int rb = m0 + sr + 128;  if (rb > cnt - 1) rb = cnt - 1;
    long arow0 = gather ? (long)tokmap[e * NB + ra] : (long)(base + ra);
    long arow1 = gather ? (long)tokmap[e * NB + rb] : (long)(base + rb);
    const f16* ap0 = A + arow0 * (long)Kd + sc;
    const f16* ap1 = A + arow1 * (long)Kd + sc;
    const f16* bp0 = Bt + ((long)e * N + n0 + sr) * (long)Kd + sc;
    const f16* bp1 = bp0 + (long)128 * Kd;
    f16* adst = As + t * 8;   // linear: row*32 + chunk*8 == t*8
    f16* bdst = Bs + t * 8;

    auto stageA = [&](int slab) {
        f16* d = adst + ((slab & 3) << 13);
        int ko = slab << 5;
        async_cp16(ap0 + ko, d);
        async_cp16(ap1 + ko, d + 4096);
    };
    auto stageB = [&](int slab) {
        f16* d = bdst + ((slab & 3) << 13);
        int ko = slab << 5;
        async_cp16(bp0 + ko, d);
        async_cp16(bp1 + ko, d + 4096);
    };

    // fragment offsets (f16 units): + mi*512 / + ni*512 per 16-row step, + slot*8192
    int aoff = (wr * 128 + ml) * 32 + kq * 8;
    int boff = (wc * 64 + ml) * 32 + kq * 8;

    f32x4 acc[8][4] = {};

    int NSl = Kd >> 5;   // 32-deep K slabs (one MFMA K-step each)

    // ---- prologue: slabs 0..2 in flight, require slab 0 landed ----
    stageA(0); stageB(0); stageA(1); stageB(1); stageA(2); stageB(2);
    asm volatile("s_waitcnt vmcnt(8)" ::: "memory");
    __builtin_amdgcn_s_barrier();

    for (int s = 0; s < NSl; ++s) {
        const f16* as = As + ((s & 3) << 13);
        const f16* bs = Bs + ((s & 3) << 13);
        // ================= phase A : M-half 0 =================
        f16x8 af[4], bf[4];
        #pragma unroll
        for (int mi = 0; mi < 4; ++mi) af[mi] = *(const f16x8*)(as + aoff + mi * 512);
        #pragma unroll
        for (int ni = 0; ni < 4; ++ni) bf[ni] = *(const f16x8*)(bs + boff + ni * 512);
        if (s + 3 < NSl) stageA(s + 3);
        __builtin_amdgcn_s_barrier();
        asm volatile("s_waitcnt lgkmcnt(0)" ::: "memory");
        __builtin_amdgcn_s_setprio(1);
        #pragma unroll
        for (int mi = 0; mi < 4; ++mi)
            #pragma unroll
            for (int ni = 0; ni < 4; ++ni)
                acc[mi][ni] = __builtin_amdgcn_mfma_f32_16x16x32_f16(af[mi], bf[ni], acc[mi][ni], 0, 0, 0);
        __builtin_amdgcn_s_setprio(0);
        __builtin_amdgcn_s_barrier();
        // ================= phase B : M-half 1 =================
        f16x8 ag[4];
        #pragma unroll
        for (int mi = 0; mi < 4; ++mi) ag[mi] = *(const f16x8*)(as + aoff + (4 + mi) * 512);
        if (s + 3 < NSl) stageB(s + 3);
        // counted gate protecting slab s+1's reads (steady: newest 4 slab-halves may
        // still be in flight = 8 ops; tail drains 4 then 0; skip on last slab)
        if (s <= NSl - 4)      asm volatile("s_waitcnt vmcnt(8)" ::: "memory");
        else if (s == NSl - 3) asm volatile("s_waitcnt vmcnt(4)" ::: "memory");
        else if (s == NSl - 2) asm volatile("s_waitcnt vmcnt(0)" ::: "memory");
        __builtin_amdgcn_s_barrier();
        asm volatile("s_waitcnt lgkmcnt(0)" ::: "memory");
        __builtin_amdgcn_s_setprio(1);
        #pragma unroll
        for (int mi = 0; mi < 4; ++mi)
            #pragma unroll
            for (int ni = 0; ni < 4; ++ni)
                acc[4 + mi][ni] = __builtin_amdgcn_mfma_f32_16x16x32_f16(ag[mi], bf[ni], acc[4 + mi][ni], 0, 0, 0);
        __builtin_amdgcn_s_setprio(0);
        __builtin_amdgcn_s_barrier();
    }

    // ---- epilogue: bias + gelu -> LDS (two 128-row passes) -> full-line 16B stores ----
    const int EP = 272;   // f16 per row: 544B stride -> kq-rows 8 banks apart, conflict-free
    int r = t >> 2;
    #pragma unroll
    for (int h = 0; h < 2; ++h) {
        if (wr == h) {
            #pragma unroll
            for (int ni = 0; ni < 4; ++ni) {
                int col = wc * 64 + ni * 16 + ml;
                float bv = bias[(long)e * N + n0 + col];
                #pragma unroll
                for (int mi = 0; mi < 8; ++mi) {
                    #pragma unroll
                    for (int rr = 0; rr < 4; ++rr) {
                        int lr = mi * 16 + kq * 4 + rr;   // 0..127 local row
                        smem[lr * EP + col] = (f16)quick_gelu(acc[mi][ni][rr] + bv);
                    }
                }
            }
        }
        __syncthreads();
        int grow = m0 + h * 128 + r;
        if (grow < cnt) {
            long gb = (long)(base + grow) * N + n0;
            #pragma unroll
            for (int j = 0; j < 8; ++j) {
                int cc = ((t & 3) + 4 * j) << 3;
                *(f16x8*)(Out + gb + cc) = *(const f16x8*)&smem[r * EP + cc];
            }
        }
        __syncthreads();
    }
}

// ---------------- LayerNorm + weighted top-4 combine ----------------
__global__ void ln_combine_k(const f16* __restrict__ y16, const float* __restrict__ lng,
                             const float* __restrict__ lnb, const int* __restrict__ eids,
                             const int* __restrict__ slots, const float* __restrict__ gatew,
                             const int* __restrict__ offp, float* __restrict__ out) {
    int b = blockIdx.x, t = threadIdx.x;
    int lane = t & 63, w = t >> 6;
    __shared__ float red[4][2];
    float o[4] = {0.f, 0.f, 0.f, 0.f};
    int c0 = t * 4;
    for (int k = 0; k < NK; k++) {
        int e = eids[b * NK + k];
        long r = offp[e] + slots[b * NK + k];
        float wk = gatew[b * NK + k];
        f16x4 hv = *(const f16x4*)(y16 + r * NC + c0);
        float v[4];
        #pragma unroll
        for (int j = 0; j < 4; j++) v[j] = (float)hv[j];
        float s = v[0] + v[1] + v[2] + v[3];
        float ss = v[0] * v[0] + v[1] * v[1] + v[2] * v[2] + v[3] * v[3];
        #pragma unroll
        for (int off = 32; off; off >>= 1) { s += __shfl_down(s, off); ss += __shfl_down(ss, off); }
        if (lane == 0) { red[w][0] = s; red[w][1] = ss; }
        __syncthreads();
        float S  = red[0][0] + red[1][0] + red[2][0] + red[3][0];
        float SS = red[0][1] + red[1][1] + red[2][1] + red[3][1];
        float mu = S * (1.f / NC);
        float var = SS * (1.f / NC) - mu * mu;
        float rs = rsqrtf(var + 1e-6f);
        #pragma unroll
        for (int j = 0; j < 4; j++) {
            float g  = lng[(long)e * NC + c0 + j];
            float bb = lnb[(long)e * NC + c0 + j];
            o[j] += wk * ((v[j] - mu) * rs * g + bb);
        }
        __syncthreads();
    }
    float4 ov = {o[0], o[1], o[2], o[3]};
    ((float4*)(out + (long)b * NC))[t] = ov;
}

extern "C" void kernel_launch(void* const* d_in, const int* in_sizes, int n_in,
                              void* d_out, int out_size, void* d_ws, size_t ws_size,
                              hipStream_t stream) {
    const float* x   = (const float*)d_in[0];
    const float* W1  = (const float*)d_in[1];
    const float* b1  = (const float*)d_in[2];
    const float* W2  = (const float*)d_in[3];
    const float* b2  = (const float*)d_in[4];
    const float* lng = (const float*)d_in[5];
    const float* lnb = (const float*)d_in[6];
    const float* Wg  = (const float*)d_in[7];
    const float* bg  = (const float*)d_in[8];
    float* out = (float*)d_out;

    char* ws = (char*)d_ws;
    size_t o = 0;
    auto take = [&](size_t bytes) { char* p = ws + o; o += (bytes + 255) & ~(size_t)255; return p; };
    f16*   x16    = (f16*)take((size_t)NB * NC * 2);
    f16*   w1t    = (f16*)take((size_t)NE * NH * NC * 2);   // [E][H][C]
    f16*   w2t    = (f16*)take((size_t)NE * NC * NH * 2);   // [E][C][H]
    f16*   h16    = (f16*)take((size_t)ROWCAP * NH * 2);
    f16*   y16    = (f16*)take((size_t)ROWCAP * NC * 2);
    int*   tokmap = (int*)take((size_t)NE * NB * 4);
    int*   eids   = (int*)take((size_t)NB * NK * 4);
    int*   slots  = (int*)take((size_t)NB * NK * 4);
    float* gatew  = (float*)take((size_t)NB * NK * 4);
    int*   counts = (int*)take(256);
    int*   offp   = (int*)take(256);

    hipMemsetAsync(counts, 0, NE * sizeof(int), stream);
    transpose_cast_k<<<dim3(NH / 32, NC / 32, NE), 256, 0, stream>>>(W1, w1t, NC, NH);
    transpose_cast_k<<<dim3(NC / 32, NH / 32, NE), 256, 0, stream>>>(W2, w2t, NH, NC);
    gating_k<<<NB, 256, 0, stream>>>(x, Wg, bg, counts, tokmap, eids, slots, gatew, x16);
    offsets_k<<<1, 64, 0, stream>>>(counts, offp);
    gemm256<<<dim3(NB / 256, NH / 256, NE), 512, 0, stream>>>(x16, w1t, b1, h16, counts, offp, tokmap, NC, NH, 1);
    gemm256<<<dim3(NB / 256, NC / 256, NE), 512, 0, stream>>>(h16, w2t, b2, y16, counts, offp, tokmap, NH, NC, 0);
    ln_combine_k<<<NB, 256, 0, stream>>>(y16, lng, lnb, eids, slots, gatew, offp, out);
}

// Round 2
// 1869.918 us; speedup vs baseline: 1.0370x; 1.0370x over previous
//
#include <hip/hip_runtime.h>

#define NB 8192   // tokens
#define NC 1024   // model dim
#define NE 8      // experts
#define NK 4      // top-k
#define NH 4096   // hidden dim
constexpr int ROWCAP = NB * NK + NE * 128;  // padded routed-row capacity

typedef _Float16 f16;
typedef _Float16 f16x8 __attribute__((ext_vector_type(8)));
typedef _Float16 f16x4 __attribute__((ext_vector_type(4)));
typedef float    f32x4 __attribute__((ext_vector_type(4)));

__device__ __forceinline__ void async_cp16(const f16* g, f16* l) {
    __builtin_amdgcn_global_load_lds((const __attribute__((address_space(1))) void*)g,
                                     (__attribute__((address_space(3))) void*)l, 16, 0, 0);
}

__device__ __forceinline__ float quick_gelu(float v) {
    return v / (1.f + __expf(-1.702f * v));
}

// ------------- transpose + cast: in [E][R][S] fp32 -> out [E][S][R] fp16 -------------
__global__ void transpose_cast_k(const float* __restrict__ in, f16* __restrict__ out,
                                 int R, int S) {
    __shared__ f16 tile[32][33];
    int e = blockIdx.z;
    long base = (long)e * R * S;
    int s0 = blockIdx.x * 32, r0 = blockIdx.y * 32;
    int tx = threadIdx.x & 31, ty = threadIdx.x >> 5;  // 32 x 8
    #pragma unroll
    for (int i = 0; i < 32; i += 8)
        tile[ty + i][tx] = (f16)in[base + (long)(r0 + ty + i) * S + s0 + tx];
    __syncthreads();
    #pragma unroll
    for (int i = 0; i < 32; i += 8)
        out[base + (long)(s0 + ty + i) * R + r0 + tx] = tile[tx][ty + i];
}

// ---- gating: logits -> softmax -> top4 -> slot assignment; also casts x -> fp16 ----
__global__ void gating_k(const float* __restrict__ x, const float* __restrict__ Wg,
                         const float* __restrict__ bg, int* __restrict__ counts,
                         int* __restrict__ tokmap, int* __restrict__ eids,
                         int* __restrict__ slots, float* __restrict__ gatew,
                         f16* __restrict__ x16) {
    int b = blockIdx.x, t = threadIdx.x;
    float acc[NE] = {};
    float4 xv = ((const float4*)(x + (long)b * NC))[t];
    f16x4 hx = { (f16)xv.x, (f16)xv.y, (f16)xv.z, (f16)xv.w };
    ((f16x4*)(x16 + (long)b * NC))[t] = hx;
    const float* wr = Wg + (long)t * 4 * NE;
    #pragma unroll
    for (int j = 0; j < 4; j++) {
        float xj = ((const float*)&xv)[j];
        #pragma unroll
        for (int e2 = 0; e2 < NE; e2++) acc[e2] += xj * wr[j * NE + e2];
    }
    #pragma unroll
    for (int e2 = 0; e2 < NE; e2++)
        #pragma unroll
        for (int off = 32; off; off >>= 1) acc[e2] += __shfl_down(acc[e2], off);
    __shared__ float red[4][NE];
    int lane = t & 63, w = t >> 6;
    if (lane == 0)
        for (int e2 = 0; e2 < NE; e2++) red[w][e2] = acc[e2];
    __syncthreads();
    if (t == 0) {
        float l[NE];
        float m = -1e30f;
        for (int e2 = 0; e2 < NE; e2++) {
            l[e2] = red[0][e2] + red[1][e2] + red[2][e2] + red[3][e2] + bg[e2];
            m = fmaxf(m, l[e2]);
        }
        float p[NE], sum = 0.f;
        for (int e2 = 0; e2 < NE; e2++) { p[e2] = __expf(l[e2] - m); sum += p[e2]; }
        float inv = 1.f / sum;
        for (int e2 = 0; e2 < NE; e2++) p[e2] *= inv;
        bool taken[NE] = {};
        for (int k = 0; k < NK; k++) {
            int be = 0; float bv = -1e30f;
            for (int e2 = 0; e2 < NE; e2++)
                if (!taken[e2] && p[e2] > bv) { bv = p[e2]; be = e2; }
            taken[be] = true;
            int slot = atomicAdd(&counts[be], 1);
            tokmap[be * NB + slot] = b;
            eids[b * NK + k] = be;
            slots[b * NK + k] = slot;
            gatew[b * NK + k] = bv;
        }
    }
}

// ---------------- padded prefix offsets ----------------
__global__ void offsets_k(const int* __restrict__ counts, int* __restrict__ offp) {
    if (threadIdx.x == 0 && blockIdx.x == 0) {
        int o = 0;
        for (int e = 0; e < NE; e++) { offp[e] = o; o += ((counts[e] + 127) >> 7) << 7; }
    }
}

// ---------------- 256x256 deep-pipelined GEMM ----------------
// Out[row,n] = quick_gelu(sum_k A[row,k]*Bt[e,n,k] + bias[e,n]), fp16 in/out, fp32 acc.
// Schedule (T3+T4+T5):
//   - K in 32-wide slabs; 4-deep LDS ring per operand (4x16KB A + 4x16KB B = 128KB).
//   - Slab layout [256 rows][4 chunks x 8 f16], XOR chunk swizzle: LDS[row][c] holds
//     global chunk c ^ ((row>>1)&3).  Staging pre-swizzles the GLOBAL source chunk so
//     the LDS dest stays linear (global_load_lds needs base + lane*16 — rule 21:
//     both-sides-or-neither).  Fragment ds_read_b128 then hits 32 banks per 8 lanes
//     -> only the free 2-way aliasing.  (Round-1 dropped this swizzle: 8-way conflict,
//     SQ_LDS_BANK_CONFLICT 31.3M, MfmaUtil 15%.)
//   - Stage 3 slabs ahead; counted vmcnt(8) once per slab (never 0 mid-loop);
//     drain tail vmcnt(4)/vmcnt(0).  2 raw s_barriers per phase, setprio around MFMA.
// 8 waves (2M x 4N), per-wave 128x64 output, acc[8][4] f32x4.
__global__ __launch_bounds__(512, 2) void gemm256(
    const f16* __restrict__ A, const f16* __restrict__ Bt,
    const float* __restrict__ bias, f16* __restrict__ Out,
    const int* __restrict__ counts, const int* __restrict__ offp,
    const int* __restrict__ tokmap, int Kd, int N, int gather) {
    int e = blockIdx.z;
    int cnt = counts[e];
    int m0 = blockIdx.x << 8;
    if (m0 >= cnt) return;
    int n0 = blockIdx.y << 8;
    int base = offp[e];

    __shared__ __align__(16) f16 smem[65536];   // 128 KB
    f16* As = smem;            // 4 slabs x 8192 f16  (256 rows x 32 k)
    f16* Bs = smem + 32768;    // 4 slabs x 8192 f16  (256 cols x 32 k)

    int t = threadIdx.x;
    int lane = t & 63;
    int w = t >> 6;
    int wr = w >> 2, wc = w & 3;          // wave tile: rows wr*128.., cols wc*64..
    int ml = lane & 15, kq = lane >> 4;   // MFMA fragment lane decomposition

    // ---- staging: thread t covers (row = t>>2 [+128], chunk = t&3).  Source chunk is
    // XOR-swizzled by (row>>1)&3 = (t>>3)&3; LDS dest linear (t*8). ----
    int sr = t >> 2;
    int sc = (((t & 3) ^ ((t >> 3) & 3)) << 3);
    int ra = m0 + sr;        if (ra > cnt - 1) ra = cnt - 1;
    int rb = m0 + sr + 128;  if (rb > cnt - 1) rb = cnt - 1;
    long arow0 = gather ? (long)tokmap[e * NB + ra] : (long)(base + ra);
    long arow1 = gather ? (long)tokmap[e * NB + rb] : (long)(base + rb);
    const f16* ap0 = A + arow0 * (long)Kd + sc;
    const f16* ap1 = A + arow1 * (long)Kd + sc;
    const f16* bp0 = Bt + ((long)e * N + n0 + sr) * (long)Kd + sc;
    const f16* bp1 = bp0 + (long)128 * Kd;
    f16* adst = As + t * 8;   // linear: row*32 + chunk*8 == t*8
    f16* bdst = Bs + t * 8;

    auto stageA = [&](int slab) {
        f16* d = adst + ((slab & 3) << 13);
        int ko = slab << 5;
        async_cp16(ap0 + ko, d);
        async_cp16(ap1 + ko, d + 4096);
    };
    auto stageB = [&](int slab) {
        f16* d = bdst + ((slab & 3) << 13);
        int ko = slab << 5;
        async_cp16(bp0 + ko, d);
        async_cp16(bp1 + ko, d + 4096);
    };

    // fragment read: chunk index kq ^ ((row>>1)&3); row bases are multiples of 16 so
    // the swizzle term is the per-lane constant (ml>>1)&3.  +mi*512 per 16-row step.
    int sxq = ((kq ^ ((ml >> 1) & 3)) << 3);
    int aoff = (wr * 128 + ml) * 32 + sxq;
    int boff = (wc * 64 + ml) * 32 + sxq;

    f32x4 acc[8][4] = {};

    int NSl = Kd >> 5;   // 32-deep K slabs (one MFMA K-step each)

    // ---- prologue: slabs 0..2 in flight, require slab 0 landed ----
    stageA(0); stageB(0); stageA(1); stageB(1); stageA(2); stageB(2);
    asm volatile("s_waitcnt vmcnt(8)" ::: "memory");
    __builtin_amdgcn_s_barrier();

    for (int s = 0; s < NSl; ++s) {
        const f16* as = As + ((s & 3) << 13);
        const f16* bs = Bs + ((s & 3) << 13);
        // ================= phase A : M-half 0 =================
        f16x8 af[4], bf[4];
        #pragma unroll
        for (int mi = 0; mi < 4; ++mi) af[mi] = *(const f16x8*)(as + aoff + mi * 512);
        #pragma unroll
        for (int ni = 0; ni < 4; ++ni) bf[ni] = *(const f16x8*)(bs + boff + ni * 512);
        if (s + 3 < NSl) stageA(s + 3);
        __builtin_amdgcn_s_barrier();
        asm volatile("s_waitcnt lgkmcnt(0)" ::: "memory");
        __builtin_amdgcn_s_setprio(1);
        #pragma unroll
        for (int mi = 0; mi < 4; ++mi)
            #pragma unroll
            for (int ni = 0; ni < 4; ++ni)
                acc[mi][ni] = __builtin_amdgcn_mfma_f32_16x16x32_f16(af[mi], bf[ni], acc[mi][ni], 0, 0, 0);
        __builtin_amdgcn_s_setprio(0);
        __builtin_amdgcn_s_barrier();
        // ================= phase B : M-half 1 =================
        f16x8 ag[4];
        #pragma unroll
        for (int mi = 0; mi < 4; ++mi) ag[mi] = *(const f16x8*)(as + aoff + (4 + mi) * 512);
        if (s + 3 < NSl) stageB(s + 3);
        // counted gate protecting slab s+1's reads (steady: newest 4 slab-halves may
        // still be in flight = 8 ops; tail drains 4 then 0; skip on last slab)
        if (s <= NSl - 4)      asm volatile("s_waitcnt vmcnt(8)" ::: "memory");
        else if (s == NSl - 3) asm volatile("s_waitcnt vmcnt(4)" ::: "memory");
        else if (s == NSl - 2) asm volatile("s_waitcnt vmcnt(0)" ::: "memory");
        __builtin_amdgcn_s_barrier();
        asm volatile("s_waitcnt lgkmcnt(0)" ::: "memory");
        __builtin_amdgcn_s_setprio(1);
        #pragma unroll
        for (int mi = 0; mi < 4; ++mi)
            #pragma unroll
            for (int ni = 0; ni < 4; ++ni)
                acc[4 + mi][ni] = __builtin_amdgcn_mfma_f32_16x16x32_f16(ag[mi], bf[ni], acc[4 + mi][ni], 0, 0, 0);
        __builtin_amdgcn_s_setprio(0);
        __builtin_amdgcn_s_barrier();
    }

    // ---- epilogue: bias + gelu -> LDS (two 128-row passes) -> full-line 16B stores ----
    const int EP = 272;   // f16 per row: 544B stride
    int r = t >> 2;
    #pragma unroll
    for (int h = 0; h < 2; ++h) {
        if (wr == h) {
            #pragma unroll
            for (int ni = 0; ni < 4; ++ni) {
                int col = wc * 64 + ni * 16 + ml;
                float bv = bias[(long)e * N + n0 + col];
                #pragma unroll
                for (int mi = 0; mi < 8; ++mi) {
                    #pragma unroll
                    for (int rr = 0; rr < 4; ++rr) {
                        int lr = mi * 16 + kq * 4 + rr;   // 0..127 local row
                        smem[lr * EP + col] = (f16)quick_gelu(acc[mi][ni][rr] + bv);
                    }
                }
            }
        }
        __syncthreads();
        int grow = m0 + h * 128 + r;
        if (grow < cnt) {
            long gb = (long)(base + grow) * N + n0;
            #pragma unroll
            for (int j = 0; j < 8; ++j) {
                int cc = ((t & 3) + 4 * j) << 3;
                *(f16x8*)(Out + gb + cc) = *(const f16x8*)&smem[r * EP + cc];
            }
        }
        __syncthreads();
    }
}

// ---------------- LayerNorm + weighted top-4 combine ----------------
__global__ void ln_combine_k(const f16* __restrict__ y16, const float* __restrict__ lng,
                             const float* __restrict__ lnb, const int* __restrict__ eids,
                             const int* __restrict__ slots, const float* __restrict__ gatew,
                             const int* __restrict__ offp, float* __restrict__ out) {
    int b = blockIdx.x, t = threadIdx.x;
    int lane = t & 63, w = t >> 6;
    __shared__ float red[4][2];
    float o[4] = {0.f, 0.f, 0.f, 0.f};
    int c0 = t * 4;
    for (int k = 0; k < NK; k++) {
        int e = eids[b * NK + k];
        long r = offp[e] + slots[b * NK + k];
        float wk = gatew[b * NK + k];
        f16x4 hv = *(const f16x4*)(y16 + r * NC + c0);
        float v[4];
        #pragma unroll
        for (int j = 0; j < 4; j++) v[j] = (float)hv[j];
        float s = v[0] + v[1] + v[2] + v[3];
        float ss = v[0] * v[0] + v[1] * v[1] + v[2] * v[2] + v[3] * v[3];
        #pragma unroll
        for (int off = 32; off; off >>= 1) { s += __shfl_down(s, off); ss += __shfl_down(ss, off); }
        if (lane == 0) { red[w][0] = s; red[w][1] = ss; }
        __syncthreads();
        float S  = red[0][0] + red[1][0] + red[2][0] + red[3][0];
        float SS = red[0][1] + red[1][1] + red[2][1] + red[3][1];
        float mu = S * (1.f / NC);
        float var = SS * (1.f / NC) - mu * mu;
        float rs = rsqrtf(var + 1e-6f);
        #pragma unroll
        for (int j = 0; j < 4; j++) {
            float g  = lng[(long)e * NC + c0 + j];
            float bb = lnb[(long)e * NC + c0 + j];
            o[j] += wk * ((v[j] - mu) * rs * g + bb);
        }
        __syncthreads();
    }
    float4 ov = {o[0], o[1], o[2], o[3]};
    ((float4*)(out + (long)b * NC))[t] = ov;
}

extern "C" void kernel_launch(void* const* d_in, const int* in_sizes, int n_in,
                              void* d_out, int out_size, void* d_ws, size_t ws_size,
                              hipStream_t stream) {
    const float* x   = (const float*)d_in[0];
    const float* W1  = (const float*)d_in[1];
    const float* b1  = (const float*)d_in[2];
    const float* W2  = (const float*)d_in[3];
    const float* b2  = (const float*)d_in[4];
    const float* lng = (const float*)d_in[5];
    const float* lnb = (const float*)d_in[6];
    const float* Wg  = (const float*)d_in[7];
    const float* bg  = (const float*)d_in[8];
    float* out = (float*)d_out;

    char* ws = (char*)d_ws;
    size_t o = 0;
    auto take = [&](size_t bytes) { char* p = ws + o; o += (bytes + 255) & ~(size_t)255; return p; };
    f16*   x16    = (f16*)take((size_t)NB * NC * 2);
    f16*   w1t    = (f16*)take((size_t)NE * NH * NC * 2);   // [E][H][C]
    f16*   w2t    = (f16*)take((size_t)NE * NC * NH * 2);   // [E][C][H]
    f16*   h16    = (f16*)take((size_t)ROWCAP * NH * 2);
    f16*   y16    = (f16*)take((size_t)ROWCAP * NC * 2);
    int*   tokmap = (int*)take((size_t)NE * NB * 4);
    int*   eids   = (int*)take((size_t)NB * NK * 4);
    int*   slots  = (int*)take((size_t)NB * NK * 4);
    float* gatew  = (float*)take((size_t)NB * NK * 4);
    int*   counts = (int*)take(256);
    int*   offp   = (int*)take(256);

    hipMemsetAsync(counts, 0, NE * sizeof(int), stream);
    transpose_cast_k<<<dim3(NH / 32, NC / 32, NE), 256, 0, stream>>>(W1, w1t, NC, NH);
    transpose_cast_k<<<dim3(NC / 32, NH / 32, NE), 256, 0, stream>>>(W2, w2t, NH, NC);
    gating_k<<<NB, 256, 0, stream>>>(x, Wg, bg, counts, tokmap, eids, slots, gatew, x16);
    offsets_k<<<1, 64, 0, stream>>>(counts, offp);
    gemm256<<<dim3(NB / 256, NH / 256, NE), 512, 0, stream>>>(x16, w1t, b1, h16, counts, offp, tokmap, NC, NH, 1);
    gemm256<<<dim3(NB / 256, NC / 256, NE), 512, 0, stream>>>(h16, w2t, b2, y16, counts, offp, tokmap, NH, NC, 0);
    ln_combine_k<<<NB, 256, 0, stream>>>(y16, lng, lnb, eids, slots, gatew, offp, out);
}

// Round 4
// 1733.430 us; speedup vs baseline: 1.1186x; 1.0787x over previous
//
#include <hip/hip_runtime.h>

#define NB 8192   // tokens
#define NC 1024   // model dim
#define NE 8      // experts
#define NK 4      // top-k
#define NH 4096   // hidden dim
constexpr int ROWCAP = NB * NK + NE * 128;  // padded routed-row capacity

typedef _Float16 f16;
typedef _Float16 f16x8 __attribute__((ext_vector_type(8)));
typedef _Float16 f16x4 __attribute__((ext_vector_type(4)));
typedef float    f32x4 __attribute__((ext_vector_type(4)));

__device__ __forceinline__ void async_cp16(const f16* g, f16* l) {
    __builtin_amdgcn_global_load_lds((const __attribute__((address_space(1))) void*)g,
                                     (__attribute__((address_space(3))) void*)l, 16, 0, 0);
}

__device__ __forceinline__ float quick_gelu(float v) {
    return v / (1.f + __expf(-1.702f * v));
}

// ------------- transpose + cast: in [E][R][S] fp32 -> out [E][S][R] fp16 -------------
__global__ void transpose_cast_k(const float* __restrict__ in, f16* __restrict__ out,
                                 int R, int S) {
    __shared__ f16 tile[32][33];
    int e = blockIdx.z;
    long base = (long)e * R * S;
    int s0 = blockIdx.x * 32, r0 = blockIdx.y * 32;
    int tx = threadIdx.x & 31, ty = threadIdx.x >> 5;  // 32 x 8
    #pragma unroll
    for (int i = 0; i < 32; i += 8)
        tile[ty + i][tx] = (f16)in[base + (long)(r0 + ty + i) * S + s0 + tx];
    __syncthreads();
    #pragma unroll
    for (int i = 0; i < 32; i += 8)
        out[base + (long)(s0 + ty + i) * R + r0 + tx] = tile[tx][ty + i];
}

// ---- gating: logits -> softmax -> top4 -> slot assignment; also casts x -> fp16 ----
__global__ void gating_k(const float* __restrict__ x, const float* __restrict__ Wg,
                         const float* __restrict__ bg, int* __restrict__ counts,
                         int* __restrict__ tokmap, int* __restrict__ eids,
                         int* __restrict__ slots, float* __restrict__ gatew,
                         f16* __restrict__ x16) {
    int b = blockIdx.x, t = threadIdx.x;
    float acc[NE] = {};
    float4 xv = ((const float4*)(x + (long)b * NC))[t];
    f16x4 hx = { (f16)xv.x, (f16)xv.y, (f16)xv.z, (f16)xv.w };
    ((f16x4*)(x16 + (long)b * NC))[t] = hx;
    const float* wr = Wg + (long)t * 4 * NE;
    #pragma unroll
    for (int j = 0; j < 4; j++) {
        float xj = ((const float*)&xv)[j];
        #pragma unroll
        for (int e2 = 0; e2 < NE; e2++) acc[e2] += xj * wr[j * NE + e2];
    }
    #pragma unroll
    for (int e2 = 0; e2 < NE; e2++)
        #pragma unroll
        for (int off = 32; off; off >>= 1) acc[e2] += __shfl_down(acc[e2], off);
    __shared__ float red[4][NE];
    int lane = t & 63, w = t >> 6;
    if (lane == 0)
        for (int e2 = 0; e2 < NE; e2++) red[w][e2] = acc[e2];
    __syncthreads();
    if (t == 0) {
        float l[NE];
        float m = -1e30f;
        for (int e2 = 0; e2 < NE; e2++) {
            l[e2] = red[0][e2] + red[1][e2] + red[2][e2] + red[3][e2] + bg[e2];
            m = fmaxf(m, l[e2]);
        }
        float p[NE], sum = 0.f;
        for (int e2 = 0; e2 < NE; e2++) { p[e2] = __expf(l[e2] - m); sum += p[e2]; }
        float inv = 1.f / sum;
        for (int e2 = 0; e2 < NE; e2++) p[e2] *= inv;
        bool taken[NE] = {};
        for (int k = 0; k < NK; k++) {
            int be = 0; float bv = -1e30f;
            for (int e2 = 0; e2 < NE; e2++)
                if (!taken[e2] && p[e2] > bv) { bv = p[e2]; be = e2; }
            taken[be] = true;
            int slot = atomicAdd(&counts[be], 1);
            tokmap[be * NB + slot] = b;
            eids[b * NK + k] = be;
            slots[b * NK + k] = slot;
            gatew[b * NK + k] = bv;
        }
    }
}

// ---------------- padded prefix offsets ----------------
__global__ void offsets_k(const int* __restrict__ counts, int* __restrict__ offp) {
    if (threadIdx.x == 0 && blockIdx.x == 0) {
        int o = 0;
        for (int e = 0; e < NE; e++) { offp[e] = o; o += ((counts[e] + 127) >> 7) << 7; }
    }
}

// ---------------- GEMM: Out[row,n] = gelu(sum_k A[row,k]*Bt[e,n,k] + bias[e,n]) ----------------
// Round-0 proven 128x128 kernel + ONE isolated change (T4 counted vmcnt):
//   - 3-slot LDS ring (3 x 16KB = 48KB).  Iter it: stage(it+2) issued at top; slab-end
//     gate is s_waitcnt vmcnt(4) — waits only for stage(it+1) (issued a full iteration
//     earlier, latency already paid), while stage(it+2) stays IN FLIGHT across the
//     barrier.  Round-0's __syncthreads() drained the just-issued prefetch every slab
//     (full-latency stall; MfmaUtil 19%).  Tail: vmcnt(0) at it==NSl-2.
//   - Race ledger: stage(it+2) writes slot (it+2)%3 == slot read at it-1; those reads
//     delivered before the it-1 end barrier (compiler waitcnts precede MFMA, which
//     precedes the barrier), and stage is issued after passing it.  Empty asm memory
//     fence after each s_barrier pins stage() against compiler hoisting (raw s_barrier
//     is not a compiler fence).
//   - XOR chunk swizzle (both-sides, rule 21) unchanged; epilogue unchanged (EP=136,
//     max idx 8695 < 24576 — round-3 died on an epilogue/LDS size mismatch).
__global__ __launch_bounds__(256) void gemm_f16(
    const f16* __restrict__ A, const f16* __restrict__ Bt,
    const float* __restrict__ bias, f16* __restrict__ Out,
    const int* __restrict__ counts, const int* __restrict__ offp,
    const int* __restrict__ tokmap, int Kd, int N, int gather) {
    int e = blockIdx.z;
    int cnt = counts[e];
    int m0 = blockIdx.x << 7;
    if (m0 >= cnt) return;
    int n0 = blockIdx.y << 7;
    int base = offp[e];

    // 3 slots x (A tile 4096 f16 | B tile 4096 f16) = 48 KB
    __shared__ __align__(16) f16 smem[24576];

    int t = threadIdx.x;
    int lane = t & 63;
    int w = t >> 6;
    int wm = (w >> 1) << 6, wn = (w & 1) << 6;

    // staging: thread t fills LDS slot (row=t>>2, chunk=t&3); global source chunk is
    // XOR-permuted so LDS dests stay lane-contiguous (global_load_lds constraint).
    int sr = m0 + (t >> 2);
    int sc = (((t & 3) ^ ((t >> 3) & 3)) << 3);
    int ca = sr < cnt - 1 ? sr : cnt - 1;
    int cb = sr + 64 < cnt - 1 ? sr + 64 : cnt - 1;
    long arow0, arow1;
    if (gather) { arow0 = tokmap[e * NB + ca]; arow1 = tokmap[e * NB + cb]; }
    else        { arow0 = base + ca;           arow1 = base + cb; }
    const f16* ap0 = A + arow0 * (long)Kd + sc;
    const f16* ap1 = A + arow1 * (long)Kd + sc;
    const f16* bp0 = Bt + ((long)e * N + n0 + (t >> 2)) * (long)Kd + sc;
    const f16* bp1 = bp0 + (long)64 * Kd;

    auto stage = [&](int slab, int slot) {
        f16* d = smem + slot * 8192 + (t << 3);
        int ko = slab << 5;
        async_cp16(ap0 + ko, d);
        async_cp16(ap1 + ko, d + 2048);
        async_cp16(bp0 + ko, d + 4096);
        async_cp16(bp1 + ko, d + 6144);
    };

    f32x4 acc[4][4] = {};
    int ml = lane & 15;
    // fragment read slot: (kq ^ swz(row)); row offsets are multiples of 16 so the
    // swizzle term is the per-lane constant (ml>>1)&3.
    int sxq = (((lane >> 4) ^ ((ml >> 1) & 3)) << 3);
    int aoff = (wm + ml) * 32 + sxq;         // + mi*512 per fragment
    int boff = (wn + ml) * 32 + sxq + 4096;  // + ni*512 per fragment

    int NSl = Kd >> 5;

    // ---- prologue: slabs 0,1 in flight; require slab 0 landed (vmcnt(4) leaves
    // stage(1)'s 4 loads flying) ----
    stage(0, 0); stage(1, 1);
    asm volatile("s_waitcnt vmcnt(4)" ::: "memory");
    __builtin_amdgcn_s_barrier();
    asm volatile("" ::: "memory");

    int sl = 0, sl2 = 2;
    for (int it = 0; it < NSl; ++it) {
        if (it + 2 < NSl) stage(it + 2, sl2);
        const f16* sb = smem + sl * 8192;
        f16x8 af[4], bf[4];
        #pragma unroll
        for (int mi = 0; mi < 4; mi++) af[mi] = *(const f16x8*)(sb + aoff + mi * 512);
        #pragma unroll
        for (int ni = 0; ni < 4; ni++) bf[ni] = *(const f16x8*)(sb + boff + ni * 512);
        asm volatile("s_waitcnt lgkmcnt(0)" ::: "memory");
        __builtin_amdgcn_s_setprio(1);
        #pragma unroll
        for (int mi = 0; mi < 4; mi++)
            #pragma unroll
            for (int ni = 0; ni < 4; ni++)
                acc[mi][ni] = __builtin_amdgcn_mfma_f32_16x16x32_f16(af[mi], bf[ni], acc[mi][ni], 0, 0, 0);
        __builtin_amdgcn_s_setprio(0);
        // counted gate: slab it+1 landed (its 4 loads are the oldest outstanding);
        // stage(it+2)'s 4 loads stay in flight across the barrier.
        if (it < NSl - 2)       asm volatile("s_waitcnt vmcnt(4)" ::: "memory");
        else if (it == NSl - 2) asm volatile("s_waitcnt vmcnt(0)" ::: "memory");
        __builtin_amdgcn_s_barrier();
        asm volatile("" ::: "memory");
        sl  = (sl  == 2) ? 0 : sl  + 1;
        sl2 = (sl2 == 2) ? 0 : sl2 + 1;
    }

    // ---- epilogue: bias + gelu -> LDS half-tile -> coalesced 16B stores ----
    const int EP = 136;   // f16 per row (272 B, 16B-aligned; quad rows land 16 banks apart)
    int rq = (lane >> 4) << 2;
    #pragma unroll
    for (int h = 0; h < 2; ++h) {
        if (wm == h * 64) {
            #pragma unroll
            for (int ni = 0; ni < 4; ni++) {
                int col = wn + ni * 16 + ml;
                float bv = bias[(long)e * N + n0 + col];
                #pragma unroll
                for (int mi = 0; mi < 4; mi++) {
                    #pragma unroll
                    for (int rr = 0; rr < 4; rr++) {
                        int lr = mi * 16 + rq + rr;   // 0..63
                        smem[lr * EP + col] = (f16)quick_gelu(acc[mi][ni][rr] + bv);
                    }
                }
            }
        }
        __syncthreads();
        int r = t >> 2;
        int grow = m0 + h * 64 + r;
        if (grow < cnt) {
            long gbase = (long)(base + grow) * N + n0;
            #pragma unroll
            for (int j = 0; j < 4; j++) {
                int cc = ((t & 3) + 4 * j) << 3;
                *(f16x8*)(Out + gbase + cc) = *(const f16x8*)&smem[r * EP + cc];
            }
        }
        __syncthreads();
    }
}

// ---------------- LayerNorm + weighted top-4 combine ----------------
__global__ void ln_combine_k(const f16* __restrict__ y16, const float* __restrict__ lng,
                             const float* __restrict__ lnb, const int* __restrict__ eids,
                             const int* __restrict__ slots, const float* __restrict__ gatew,
                             const int* __restrict__ offp, float* __restrict__ out) {
    int b = blockIdx.x, t = threadIdx.x;
    int lane = t & 63, w = t >> 6;
    __shared__ float red[4][2];
    float o[4] = {0.f, 0.f, 0.f, 0.f};
    int c0 = t * 4;
    for (int k = 0; k < NK; k++) {
        int e = eids[b * NK + k];
        long r = offp[e] + slots[b * NK + k];
        float wk = gatew[b * NK + k];
        f16x4 hv = *(const f16x4*)(y16 + r * NC + c0);
        float v[4];
        #pragma unroll
        for (int j = 0; j < 4; j++) v[j] = (float)hv[j];
        float s = v[0] + v[1] + v[2] + v[3];
        float ss = v[0] * v[0] + v[1] * v[1] + v[2] * v[2] + v[3] * v[3];
        #pragma unroll
        for (int off = 32; off; off >>= 1) { s += __shfl_down(s, off); ss += __shfl_down(ss, off); }
        if (lane == 0) { red[w][0] = s; red[w][1] = ss; }
        __syncthreads();
        float S  = red[0][0] + red[1][0] + red[2][0] + red[3][0];
        float SS = red[0][1] + red[1][1] + red[2][1] + red[3][1];
        float mu = S * (1.f / NC);
        float var = SS * (1.f / NC) - mu * mu;
        float rs = rsqrtf(var + 1e-6f);
        #pragma unroll
        for (int j = 0; j < 4; j++) {
            float g  = lng[(long)e * NC + c0 + j];
            float bb = lnb[(long)e * NC + c0 + j];
            o[j] += wk * ((v[j] - mu) * rs * g + bb);
        }
        __syncthreads();
    }
    float4 ov = {o[0], o[1], o[2], o[3]};
    ((float4*)(out + (long)b * NC))[t] = ov;
}

extern "C" void kernel_launch(void* const* d_in, const int* in_sizes, int n_in,
                              void* d_out, int out_size, void* d_ws, size_t ws_size,
                              hipStream_t stream) {
    const float* x   = (const float*)d_in[0];
    const float* W1  = (const float*)d_in[1];
    const float* b1  = (const float*)d_in[2];
    const float* W2  = (const float*)d_in[3];
    const float* b2  = (const float*)d_in[4];
    const float* lng = (const float*)d_in[5];
    const float* lnb = (const float*)d_in[6];
    const float* Wg  = (const float*)d_in[7];
    const float* bg  = (const float*)d_in[8];
    float* out = (float*)d_out;

    char* ws = (char*)d_ws;
    size_t o = 0;
    auto take = [&](size_t bytes) { char* p = ws + o; o += (bytes + 255) & ~(size_t)255; return p; };
    f16*   x16    = (f16*)take((size_t)NB * NC * 2);
    f16*   w1t    = (f16*)take((size_t)NE * NH * NC * 2);   // [E][H][C]
    f16*   w2t    = (f16*)take((size_t)NE * NC * NH * 2);   // [E][C][H]
    f16*   h16    = (f16*)take((size_t)ROWCAP * NH * 2);
    f16*   y16    = (f16*)take((size_t)ROWCAP * NC * 2);
    int*   tokmap = (int*)take((size_t)NE * NB * 4);
    int*   eids   = (int*)take((size_t)NB * NK * 4);
    int*   slots  = (int*)take((size_t)NB * NK * 4);
    float* gatew  = (float*)take((size_t)NB * NK * 4);
    int*   counts = (int*)take(256);
    int*   offp   = (int*)take(256);

    hipMemsetAsync(counts, 0, NE * sizeof(int), stream);
    transpose_cast_k<<<dim3(NH / 32, NC / 32, NE), 256, 0, stream>>>(W1, w1t, NC, NH);
    transpose_cast_k<<<dim3(NC / 32, NH / 32, NE), 256, 0, stream>>>(W2, w2t, NH, NC);
    gating_k<<<NB, 256, 0, stream>>>(x, Wg, bg, counts, tokmap, eids, slots, gatew, x16);
    offsets_k<<<1, 64, 0, stream>>>(counts, offp);
    gemm_f16<<<dim3(64, NH / 128, NE), 256, 0, stream>>>(x16, w1t, b1, h16, counts, offp, tokmap, NC, NH, 1);
    gemm_f16<<<dim3(64, NC / 128, NE), 256, 0, stream>>>(h16, w2t, b2, y16, counts, offp, tokmap, NH, NC, 0);
    ln_combine_k<<<NB, 256, 0, stream>>>(y16, lng, lnb, eids, slots, gatew, offp, out);
}